// Round 1
// 1494.759 us; speedup vs baseline: 1.0024x; 1.0024x over previous
//
#include <hip/hip_runtime.h>

#define NSV 20
#define SS  1000

typedef __bf16 bf16_t;
typedef __bf16 bf16x8 __attribute__((ext_vector_type(8)));
typedef float  f32x4  __attribute__((ext_vector_type(4)));
typedef _Float16 f16x8 __attribute__((ext_vector_type(8)));
typedef _Float16 f16x4 __attribute__((ext_vector_type(4)));

__device__ __forceinline__ float selu_f(float v) {
    const float scale = 1.0507009873554805f;
    const float alpha = 1.6732632423543772f;
    return v > 0.f ? scale * v : scale * alpha * expm1f(v);
}

// fast selu for the RNN (exp-1 instead of expm1: abs err <= ~1.7e-7, negligible)
__device__ __forceinline__ float selu_fast(float v) {
    const float scale = 1.0507009873554805f;
    const float sa    = 1.7580993408473766f;   // scale*alpha
    return v > 0.f ? scale * v : sa * (__expf(v) - 1.0f);
}

// ---------------------------------------------------------------------------
// Precompute M = W0s @ W3  (128x128) and c = W0s @ b3 (128), where
// W0s = gw0[:, 6:26]. z-state fusion: z += dt*(M·hC + c).
// ---------------------------------------------------------------------------
__global__ void prep_m(const float* __restrict__ gw0, const float* __restrict__ gw3,
                       const float* __restrict__ gb3,
                       float* __restrict__ Mm, float* __restrict__ Mc)
{
    int idx = blockIdx.x * blockDim.x + threadIdx.x;
    if (idx < 128 * 128) {
        int j = idx >> 7, k = idx & 127;
        float s = 0.f;
#pragma unroll
        for (int t = 0; t < NSV; ++t)
            s = fmaf(gw0[j * 26 + 6 + t], gw3[t * 128 + k], s);
        Mm[idx] = s;
    } else if (idx < 128 * 128 + 128) {
        int j = idx - 128 * 128;
        float s = 0.f;
#pragma unroll
        for (int t = 0; t < NSV; ++t)
            s = fmaf(gw0[j * 26 + 6 + t], gb3[t], s);
        Mc[j] = s;
    }
}

// ---------------------------------------------------------------------------
// MFMA RNN: 16 batch rows per block, 16 blocks, 512 threads (8 waves).
// Wave w owns output strip w (units w*16..w*16+15). Per phase:
//   D[16 units x 16 batches] = A(W-strip, f16 hi+lo regs) @ B(h, f16 LDS).
// Weight hi/lo split: W = Whi + Wlo (both f16) -> 2 MFMAs/chunk, weight
// quantization error ~2^-22; only the f16 h-exchange keeps a 2^-11 term.
// z (=W0s·sv) and sv integrate in fp32; eps path fp32 on VALU (exact).
// LDS h layout: [batch n][unit k] f16, byte ^= ((n&7)<<4) swizzle
// (2-way bank sharing per 16-lane group = free). 3 barriers/step.
// Waves 0-1 additionally compute W3·hC for statevar; waves 6-7 stage eps.
// ---------------------------------------------------------------------------
__global__ __launch_bounds__(512, 2) void rnn_kernel(
    const float* __restrict__ x,
    const float* __restrict__ gw0, const float* __restrict__ gb0,
    const float* __restrict__ gw1, const float* __restrict__ gb1,
    const float* __restrict__ gw2, const float* __restrict__ gb2,
    const float* __restrict__ gw3, const float* __restrict__ gb3,
    const float* __restrict__ Mm, const float* __restrict__ Mc,
    float* __restrict__ statevar)
{
    const int tid  = threadIdx.x;
    const int wv   = tid >> 6;        // wave 0..7 = output strip
    const int lane = tid & 63;
    const int col  = lane & 15;       // batch within block (B/D col)
    const int quad = lane >> 4;
    const int b0   = blockIdx.x * 16;

    __shared__ _Float16 hA[2048];     // [16 n][128 k] f16, swizzled
    __shared__ _Float16 hB[2048];
    __shared__ _Float16 hC[2048];
    __shared__ float    epsb[2][16][8];

    const int swz = (col & 7) << 4;
    int rdoff[4];
#pragma unroll
    for (int ks = 0; ks < 4; ++ks)
        rdoff[ks] = (col * 256 + ks * 64 + quad * 16) ^ swz;
    const int wroff = (col * 256 + (wv * 16 + quad * 4) * 2) ^ swz;

    // ---- weights into registers as f16 hi/lo A-fragments ----
    // A-frag: lane holds W[row = wv*16 + (lane&15)][k = ks*32 + quad*8 + j]
    const int arow = wv * 16 + col;
    f16x8 w1h[4], w1l[4], w2h[4], w2l[4], wmh[4], wml[4];
#pragma unroll
    for (int ks = 0; ks < 4; ++ks) {
        const float* p1 = gw1 + arow * 128 + ks * 32 + quad * 8;
        const float* p2 = gw2 + arow * 128 + ks * 32 + quad * 8;
        const float* pm = Mm  + arow * 128 + ks * 32 + quad * 8;
#pragma unroll
        for (int j = 0; j < 8; ++j) {
            float v1 = p1[j]; _Float16 h1 = (_Float16)v1;
            w1h[ks][j] = h1; w1l[ks][j] = (_Float16)(v1 - (float)h1);
            float v2 = p2[j]; _Float16 h2 = (_Float16)v2;
            w2h[ks][j] = h2; w2l[ks][j] = (_Float16)(v2 - (float)h2);
            float vm = pm[j]; _Float16 hm = (_Float16)vm;
            wmh[ks][j] = hm; wml[ks][j] = (_Float16)(vm - (float)hm);
        }
    }
    const bool svwave = (wv < 2);     // waves 0,1: W3 strips (rows 0..31, >=20 zero)
    f16x8 w3h[4];
    {
        const int r3 = wv * 16 + col;
#pragma unroll
        for (int ks = 0; ks < 4; ++ks) {
#pragma unroll
            for (int j = 0; j < 8; ++j) {
                float v = (svwave && r3 < NSV) ? gw3[r3 * 128 + ks * 32 + quad * 8 + j] : 0.f;
                w3h[ks][j] = (_Float16)v;
            }
        }
    }

    // per-lane D-row constants (unit u = wv*16 + quad*4 + r)
    float b1v[4], b2v[4], cjv[4], b0v[4], b3v[4], w0e[4][6];
#pragma unroll
    for (int r = 0; r < 4; ++r) {
        const int u = wv * 16 + quad * 4 + r;
        b1v[r] = gb1[u]; b2v[r] = gb2[u]; cjv[r] = Mc[u]; b0v[r] = gb0[u];
#pragma unroll
        for (int i = 0; i < 6; ++i) w0e[r][i] = gw0[u * 26 + i];
        b3v[r] = (svwave && u < NSV) ? gb3[u] : 0.f;
    }

    // eps register pipeline: waves 6-7 (tid 416..511) hold eps(t+1)
    const bool epsw = (tid >= 416);
    int pb = 0, pi = 0;
    if (epsw) { int p = tid - 416; pb = p / 6; pi = p - pb * 6; }
    const float* xp = x + (b0 + pb) * (SS * 13);
    float r_eps = 0.f;
    if (epsw) r_eps = xp[13 + 1 + pi];   // eps(1)

    // prologue: hA(0) = selu(W0e·eps(0) + b0), z(0)=0
    const float* xq = x + (b0 + col) * (SS * 13);
    float e0[6];
#pragma unroll
    for (int i = 0; i < 6; ++i) e0[i] = xq[1 + i];

    float z[4]  = {0.f, 0.f, 0.f, 0.f};
    float sv[4] = {0.f, 0.f, 0.f, 0.f};
    const int svbase = (b0 + col) * (SS * NSV) + wv * 16 + quad * 4;

    {
        f16x4 pk;
#pragma unroll
        for (int r = 0; r < 4; ++r) {
            float e = b0v[r];
#pragma unroll
            for (int i = 0; i < 6; ++i) e = fmaf(w0e[r][i], e0[i], e);
            pk[r] = (_Float16)selu_fast(e);
        }
        *(f16x4*)((char*)hA + wroff) = pk;
    }
    if (tid < 320) statevar[(b0 + tid / 20) * (SS * NSV) + (tid % 20)] = 0.f;
    __syncthreads();

#define LOADB(BUF, BF)                                                        \
    do {                                                                      \
        _Pragma("unroll")                                                     \
        for (int ks_ = 0; ks_ < 4; ++ks_)                                     \
            BF[ks_] = *(const f16x8*)((const char*)(BUF) + rdoff[ks_]);       \
    } while (0)

#define MM2(WH, WL, BF, OUT)                                                  \
    do {                                                                      \
        f32x4 a0_ = {0.f, 0.f, 0.f, 0.f}, a1_ = {0.f, 0.f, 0.f, 0.f};        \
        _Pragma("unroll")                                                     \
        for (int ks_ = 0; ks_ < 4; ++ks_) {                                   \
            a0_ = __builtin_amdgcn_mfma_f32_16x16x32_f16(WH[ks_], BF[ks_], a0_, 0, 0, 0); \
            a1_ = __builtin_amdgcn_mfma_f32_16x16x32_f16(WL[ks_], BF[ks_], a1_, 0, 0, 0); \
        }                                                                     \
        OUT = a0_ + a1_;                                                      \
    } while (0)

#define STOREH(BUF, H0, H1, H2, H3)                                           \
    do {                                                                      \
        f16x4 pk_;                                                            \
        pk_[0] = (_Float16)(H0); pk_[1] = (_Float16)(H1);                     \
        pk_[2] = (_Float16)(H2); pk_[3] = (_Float16)(H3);                     \
        *(f16x4*)((char*)(BUF) + wroff) = pk_;                                \
    } while (0)

    for (int t = 0; t < SS - 1; ++t) {
        // ---- Phase A: hB = selu(W1·hA + b1) ----
        {
            f16x8 bf[4]; LOADB(hA, bf);
            f32x4 s; MM2(w1h, w1l, bf, s);
            STOREH(hB, selu_fast(s[0] + b1v[0]), selu_fast(s[1] + b1v[1]),
                       selu_fast(s[2] + b1v[2]), selu_fast(s[3] + b1v[3]));
        }
        __syncthreads();

        // ---- Phase B: hC = selu(W2·hB + b2); eps pipeline advance ----
        {
            f16x8 bf[4]; LOADB(hB, bf);
            f32x4 s; MM2(w2h, w2l, bf, s);
            STOREH(hC, selu_fast(s[0] + b2v[0]), selu_fast(s[1] + b2v[1]),
                       selu_fast(s[2] + b2v[2]), selu_fast(s[3] + b2v[3]));
        }
        if (epsw) {
            epsb[(t + 1) & 1][pb][pi] = r_eps;
            if (t + 2 < SS) r_eps = xp[(t + 2) * 13 + 1 + pi];
        }
        __syncthreads();

        // ---- Phase C: z += dt(M·hC + c); hA' = selu(z + W0e·eps' + b0);
        //      waves 0-1: sv += dt(W3·hC + b3) -> statevar ----
        {
            f16x8 bf[4]; LOADB(hC, bf);
            const float dtv = 0.01f * (float)(t + 1) - 0.01f * (float)t;
            f32x4 dm; MM2(wmh, wml, bf, dm);
            if (svwave) {
                f32x4 d3 = {0.f, 0.f, 0.f, 0.f};
#pragma unroll
                for (int ks = 0; ks < 4; ++ks)
                    d3 = __builtin_amdgcn_mfma_f32_16x16x32_f16(w3h[ks], bf[ks], d3, 0, 0, 0);
#pragma unroll
                for (int r = 0; r < 4; ++r) sv[r] = fmaf(dtv, d3[r] + b3v[r], sv[r]);
                if (wv == 0 || quad == 0) {   // valid sv rows only (0..19)
                    float4 st; st.x = sv[0]; st.y = sv[1]; st.z = sv[2]; st.w = sv[3];
                    *(float4*)&statevar[svbase + (t + 1) * NSV] = st;
                }
            }
            const float* eb = epsb[(t + 1) & 1][col];
            float ep[6];
#pragma unroll
            for (int i = 0; i < 6; ++i) ep[i] = eb[i];
            float hv[4];
#pragma unroll
            for (int r = 0; r < 4; ++r) {
                z[r] = fmaf(dtv, dm[r] + cjv[r], z[r]);
                float e = b0v[r];
#pragma unroll
                for (int i = 0; i < 6; ++i) e = fmaf(w0e[r][i], ep[i], e);
                hv[r] = selu_fast(z[r] + e);
            }
            STOREH(hA, hv[0], hv[1], hv[2], hv[3]);
        }
        __syncthreads();
    }
#undef LOADB
#undef MM2
#undef STOREH
}

// ---------------------------------------------------------------------------
// Weight prep: fp32 -> bf16, pad fw3 from [6][256] to [16][256] with zeros.
// ---------------------------------------------------------------------------
__global__ void prep_weights(
    const float* __restrict__ fw0, const float* __restrict__ fw1,
    const float* __restrict__ fw2, const float* __restrict__ fw3,
    bf16_t* __restrict__ w0b, bf16_t* __restrict__ w1b,
    bf16_t* __restrict__ w2b, bf16_t* __restrict__ w3b)
{
    const int i      = blockIdx.x * blockDim.x + threadIdx.x;
    const int stride = gridDim.x * blockDim.x;
    for (int k = i; k < 256 * 32;  k += stride) w0b[k] = (bf16_t)fw0[k];
    for (int k = i; k < 256 * 256; k += stride) w1b[k] = (bf16_t)fw1[k];
    for (int k = i; k < 256 * 256; k += stride) w2b[k] = (bf16_t)fw2[k];
    for (int k = i; k < 16 * 256;  k += stride) {
        int row = k >> 8, col = k & 255;
        w3b[k] = (row < 6) ? (bf16_t)fw3[row * 256 + col] : (bf16_t)0.f;
    }
}

// ---------------------------------------------------------------------------
// Fused F-MLP: 64-row tiles, bf16 MFMA 16x16x32, fp32 accumulate.
// ---------------------------------------------------------------------------
#define LDA 264   // 256 + 8 pad

template <int K>
__device__ __forceinline__ void mlp_layer(
    bf16_t* __restrict__ A, const bf16_t* __restrict__ Wb,
    const float* __restrict__ bias, int wave, int lane, bool do_selu)
{
    f32x4 acc[4][4];
#pragma unroll
    for (int mt = 0; mt < 4; ++mt)
#pragma unroll
        for (int nt = 0; nt < 4; ++nt) acc[mt][nt] = (f32x4){0.f, 0.f, 0.f, 0.f};

    const int colbase = wave * 64;
    const int mrow = lane & 15;
    const int quad = lane >> 4;

#pragma unroll
    for (int ks = 0; ks < K / 32; ++ks) {
        bf16x8 af[4], bfr[4];
#pragma unroll
        for (int mt = 0; mt < 4; ++mt)
            af[mt] = *(const bf16x8*)&A[(mt * 16 + mrow) * LDA + ks * 32 + quad * 8];
#pragma unroll
        for (int nt = 0; nt < 4; ++nt)
            bfr[nt] = *(const bf16x8*)&Wb[(colbase + nt * 16 + mrow) * K + ks * 32 + quad * 8];
#pragma unroll
        for (int mt = 0; mt < 4; ++mt)
#pragma unroll
            for (int nt = 0; nt < 4; ++nt)
                acc[mt][nt] = __builtin_amdgcn_mfma_f32_16x16x32_bf16(
                    af[mt], bfr[nt], acc[mt][nt], 0, 0, 0);
    }
    __syncthreads();

#pragma unroll
    for (int nt = 0; nt < 4; ++nt) {
        const int col = colbase + nt * 16 + mrow;
        const float bv = bias[col];
#pragma unroll
        for (int mt = 0; mt < 4; ++mt) {
#pragma unroll
            for (int rI = 0; rI < 4; ++rI) {
                int row = mt * 16 + quad * 4 + rI;
                float v = acc[mt][nt][rI] + bv;
                if (do_selu) v = selu_f(v);
                A[row * LDA + col] = (bf16_t)v;
            }
        }
    }
    __syncthreads();
}

__global__ __launch_bounds__(256) void fmlp_kernel(
    const float* __restrict__ x, const float* __restrict__ statevar,
    const bf16_t* __restrict__ w0b, const bf16_t* __restrict__ w1b,
    const bf16_t* __restrict__ w2b, const bf16_t* __restrict__ w3b,
    const float* __restrict__ fb0, const float* __restrict__ fb1,
    const float* __restrict__ fb2, const float* __restrict__ fb3,
    float* __restrict__ out)
{
    __shared__ bf16_t A[64 * LDA];

    const int tid  = threadIdx.x;
    const int wave = tid >> 6;
    const int lane = tid & 63;
    const int r0   = blockIdx.x * 64;

    {
        const int r = tid >> 2;
        const int q = tid & 3;
        const int g = r0 + r;
        const float* xr  = x + g * 13;
        const float* svr = statevar + g * NSV;
#pragma unroll
        for (int i = 0; i < 8; ++i) {
            int c = q * 8 + i;
            float v = (c < 12) ? xr[c + 1] : svr[c - 12];
            A[r * LDA + c] = (bf16_t)v;
        }
    }
    __syncthreads();

    mlp_layer<32>(A, w0b, fb0, wave, lane, true);
    mlp_layer<256>(A, w1b, fb1, wave, lane, true);
    mlp_layer<256>(A, w2b, fb2, wave, lane, true);

    {
        const int mrow = lane & 15;
        const int quad = lane >> 4;
        f32x4 acc = (f32x4){0.f, 0.f, 0.f, 0.f};
#pragma unroll
        for (int ks = 0; ks < 8; ++ks) {
            bf16x8 af  = *(const bf16x8*)&A[(wave * 16 + mrow) * LDA + ks * 32 + quad * 8];
            bf16x8 bfr = *(const bf16x8*)&w3b[mrow * 256 + ks * 32 + quad * 8];
            acc = __builtin_amdgcn_mfma_f32_16x16x32_bf16(af, bfr, acc, 0, 0, 0);
        }
        const int col = mrow;
        if (col < 6) {
            const float bv = fb3[col];
#pragma unroll
            for (int rI = 0; rI < 4; ++rI) {
                int row = wave * 16 + quad * 4 + rI;
                int g = r0 + row;
                out[g * 6 + col] = acc[rI] + bv;
            }
        }
    }
}

// ---------------------------------------------------------------------------
extern "C" void kernel_launch(void* const* d_in, const int* in_sizes, int n_in,
                              void* d_out, int out_size, void* d_ws, size_t ws_size,
                              hipStream_t stream)
{
    const float* x   = (const float*)d_in[0];
    const float* gw0 = (const float*)d_in[1];
    const float* gb0 = (const float*)d_in[2];
    const float* gw1 = (const float*)d_in[3];
    const float* gb1 = (const float*)d_in[4];
    const float* gw2 = (const float*)d_in[5];
    const float* gb2 = (const float*)d_in[6];
    const float* gw3 = (const float*)d_in[7];
    const float* gb3 = (const float*)d_in[8];
    const float* fw0 = (const float*)d_in[9];
    const float* fb0 = (const float*)d_in[10];
    const float* fw1 = (const float*)d_in[11];
    const float* fb1 = (const float*)d_in[12];
    const float* fw2 = (const float*)d_in[13];
    const float* fb2 = (const float*)d_in[14];
    const float* fw3 = (const float*)d_in[15];
    const float* fb3 = (const float*)d_in[16];

    // workspace layout
    float* statevar = (float*)d_ws;                              // 20,480,000 B
    bf16_t* w0b = (bf16_t*)((char*)d_ws + 20480000);             // 16,384 B
    bf16_t* w1b = w0b + 256 * 32;                                // 131,072 B
    bf16_t* w2b = w1b + 256 * 256;                               // 131,072 B
    bf16_t* w3b = w2b + 256 * 256;                               // 8,192 B
    float*  Mm  = (float*)((char*)d_ws + 20766720);              // 65,536 B
    float*  Mc  = (float*)((char*)d_ws + 20832256);              // 512 B

    prep_weights<<<64, 256, 0, stream>>>(fw0, fw1, fw2, fw3, w0b, w1b, w2b, w3b);
    prep_m<<<65, 256, 0, stream>>>(gw0, gw3, gb3, Mm, Mc);
    rnn_kernel<<<16, 512, 0, stream>>>(x, gw0, gb0, gw1, gb1, gw2, gb2,
                                       gw3, gb3, Mm, Mc, statevar);
    fmlp_kernel<<<4000, 256, 0, stream>>>(x, statevar, w0b, w1b, w2b, w3b,
                                          fb0, fb1, fb2, fb3, (float*)d_out);
}